// Round 6
// baseline (715.707 us; speedup 1.0000x reference)
//
#include <hip/hip_runtime.h>
#include <math.h>
#include <stdint.h>

#define S_LEN 2048
#define D_DIM 4096
#define NHEAD 32
#define HDIM  128

typedef int      v4i __attribute__((ext_vector_type(4)));
typedef float    v4f __attribute__((ext_vector_type(4)));
typedef _Float16 v8h __attribute__((ext_vector_type(8)));

__device__ __forceinline__ float quant128(float x) {
  return fminf(fmaxf(rintf(x / 0.1f), -128.f), 127.f);
}
// async 16B global->LDS DMA; LDS side is wave-uniform base + lane*16
__device__ __forceinline__ void gl_lds16(const void* g, void* l) {
  __builtin_amdgcn_global_load_lds(
      (const __attribute__((address_space(1))) void*)g,
      (__attribute__((address_space(3))) void*)l, 16, 0, 0);
}

// ---------------- prep kernels ----------------
__global__ __launch_bounds__(256) void quant_hidden_k(const float* __restrict__ in,
                                                      int8_t* __restrict__ out) {
  const int idx = blockIdx.x * 256 + threadIdx.x;
  const float4 v = ((const float4*)in)[idx];
  const int q0 = (int)quant128(v.x), q1 = (int)quant128(v.y);
  const int q2 = (int)quant128(v.z), q3 = (int)quant128(v.w);
  ((int*)out)[idx] = (q0 & 0xff) | ((q1 & 0xff) << 8) | ((q2 & 0xff) << 16) | ((q3 & 0xff) << 24);
}

// fused f32->int8 convert of wq,wk,wv into one contiguous 48MB dst
__global__ __launch_bounds__(256) void wconv3_k(const float* __restrict__ a,
                                                const float* __restrict__ b,
                                                const float* __restrict__ c,
                                                int8_t* __restrict__ out) {
  const int which = blockIdx.x >> 14;
  const int sub = blockIdx.x & 16383;
  const float* src = (which == 0) ? a : (which == 1) ? b : c;
  const int idx = sub * 256 + threadIdx.x;
  const float4 v = ((const float4*)src)[idx];  // int4-valued floats, exact
  const int q0 = __float2int_rn(v.x), q1 = __float2int_rn(v.y);
  const int q2 = __float2int_rn(v.z), q3 = __float2int_rn(v.w);
  ((int*)out)[(size_t)which * 4194304 + idx] =
      (q0 & 0xff) | ((q1 & 0xff) << 8) | ((q2 & 0xff) << 16) | ((q3 & 0xff) << 24);
}

__global__ __launch_bounds__(256) void wconv_k(const float* __restrict__ in,
                                               int8_t* __restrict__ out) {
  const int idx = blockIdx.x * 256 + threadIdx.x;
  const float4 v = ((const float4*)in)[idx];
  const int q0 = __float2int_rn(v.x), q1 = __float2int_rn(v.y);
  const int q2 = __float2int_rn(v.z), q3 = __float2int_rn(v.w);
  ((int*)out)[idx] = (q0 & 0xff) | ((q1 & 0xff) << 8) | ((q2 & 0xff) << 16) | ((q3 & 0xff) << 24);
}

__global__ __launch_bounds__(256) void rope_tab_k(const int* __restrict__ pos,
                                                  float* __restrict__ ct,
                                                  float* __restrict__ st) {
  const int idx = blockIdx.x * 256 + threadIdx.x;  // [S][64]
  const int s = idx >> 6, j = idx & 63;
  const float inv = exp2f((float)j * -0.20762050593046016f);  // 10000^(-j/64)
  const float a = (float)pos[s] * inv;
  float si, c;
  sincosf(a, &si, &c);
  ct[idx] = c;
  st[idx] = si;
}

// ---------------------------------------------------------------------------
// int8 MFMA GEMM v4: BK=128, global_load_lds staging, XOR-swizzled LDS rows.
// XCD-aware block decode: consecutive blockIdx round-robin across XCDs, so
// blocks with B%8==x land on XCD x; give XCD x the n-tile band 4x..4x+3 ->
// per-XCD weight footprint 2 MB (L2-resident). Within the band, 4 consecutive
// blocks share the same m-band of A.
// ---------------------------------------------------------------------------
template <int OMODE>
__global__ __launch_bounds__(256) void gemm_i8(
    const int8_t* __restrict__ A8, const int8_t* __restrict__ W8,
    const float* __restrict__ wsc, const float* __restrict__ ctab,
    const float* __restrict__ stab, void* __restrict__ outp) {
  __shared__ __align__(16) int8_t Als[16384];  // 128 rows x 128 B
  __shared__ __align__(16) int8_t Bls[16384];
  const int t = threadIdx.x;
  const int w = t >> 6, lane = t & 63, g = lane >> 4, l15 = lane & 15;
  // XCD-cluster decode: x = B&7 (XCD), k = B>>3: n_local = k&3, m = k>>2
  const int G = blockIdx.x;
  const int xcd = G & 7, kk2 = G >> 3;
  const int bn = ((xcd << 2) + (kk2 & 3)) * 128;  // 32 n-tiles, banded per XCD
  const int bm = (kk2 >> 2) * 128;                // 16 m-tiles

  // staging: wave w owns rows w*32 .. w*32+31 (4 DMA instrs x 8 rows each).
  const int srow = lane >> 3;                   // row within 8-row segment
  const int schunk = ((lane & 7) ^ srow) * 16;  // source chunk swizzle
  const int8_t* sA[4];
  const int8_t* sB[4];
  int8_t* dA[4];
  int8_t* dB[4];
#pragma unroll
  for (int i = 0; i < 4; ++i) {
    const int row = w * 32 + i * 8 + srow;
    sA[i] = A8 + (size_t)(bm + row) * D_DIM + schunk;
    sB[i] = W8 + (size_t)(bn + row) * D_DIM + schunk;
    dA[i] = Als + w * 4096 + i * 1024;
    dB[i] = Bls + w * 4096 + i * 1024;
  }

  v4i acc[8][2];
#pragma unroll
  for (int i = 0; i < 8; ++i) {
    acc[i][0] = (v4i){0, 0, 0, 0};
    acc[i][1] = (v4i){0, 0, 0, 0};
  }

  for (int k0 = 0; k0 < D_DIM; k0 += 128) {
#pragma unroll
    for (int i = 0; i < 4; ++i) {
      gl_lds16(sA[i] + k0, dA[i]);
      gl_lds16(sB[i] + k0, dB[i]);
    }
    __syncthreads();  // vmcnt drained before frag reads
#pragma unroll
    for (int kk = 0; kk < 2; ++kk) {
      const int coff = (((kk << 2) | g) ^ (l15 & 7)) * 16;
      const v4i bf0 = *(const v4i*)(Bls + (w * 16 + l15) * 128 + coff);
      const v4i bf1 = *(const v4i*)(Bls + (w * 16 + 64 + l15) * 128 + coff);
#pragma unroll
      for (int mi = 0; mi < 8; ++mi) {
        const v4i af = *(const v4i*)(Als + (mi * 16 + l15) * 128 + coff);
        acc[mi][0] = __builtin_amdgcn_mfma_i32_16x16x64_i8(af, bf0, acc[mi][0], 0, 0, 0);
        acc[mi][1] = __builtin_amdgcn_mfma_i32_16x16x64_i8(af, bf1, acc[mi][1], 0, 0, 0);
      }
    }
    __syncthreads();  // reads done before next DMA overwrites
  }

  if (OMODE == 0 || OMODE == 1) {
    const int jcol = w * 16 + l15;  // 0..63 (head spans the 128-col tile)
    const float sc0 = 0.1f * wsc[bn + jcol];
    const float sc1 = 0.1f * wsc[bn + jcol + 64];
    int8_t* dst = (int8_t*)outp;
#pragma unroll
    for (int mi = 0; mi < 8; ++mi) {
#pragma unroll
      for (int r = 0; r < 4; ++r) {
        const int s = bm + mi * 16 + g * 4 + r;
        const float c = ctab[s * 64 + jcol];
        const float si = stab[s * 64 + jcol];
        const float x1 = (float)acc[mi][0][r] * sc0;
        const float x2 = (float)acc[mi][1][r] * sc1;
        dst[(size_t)s * D_DIM + bn + jcol] = (int8_t)quant128(x1 * c - x2 * si);
        dst[(size_t)s * D_DIM + bn + jcol + 64] = (int8_t)quant128(x2 * c + x1 * si);
      }
    }
  } else if (OMODE == 2) {
    _Float16* dst = (_Float16*)outp;  // quantized V value (int <=128, exact in f16)
#pragma unroll
    for (int jt = 0; jt < 2; ++jt) {
      const int col = bn + w * 16 + jt * 64 + l15;
      const float scv = 0.1f * wsc[col];
#pragma unroll
      for (int mi = 0; mi < 8; ++mi) {
#pragma unroll
        for (int r = 0; r < 4; ++r) {
          const int s = bm + mi * 16 + g * 4 + r;
          dst[(size_t)col * S_LEN + s] = (_Float16)quant128((float)acc[mi][jt][r] * scv);
        }
      }
    }
  } else {
    float* dst = (float*)outp;
#pragma unroll
    for (int jt = 0; jt < 2; ++jt) {
      const int col = bn + w * 16 + jt * 64 + l15;
      const float scv = 0.1f * wsc[col];
#pragma unroll
      for (int mi = 0; mi < 8; ++mi) {
#pragma unroll
        for (int r = 0; r < 4; ++r) {
          const int s = bm + mi * 16 + g * 4 + r;
          dst[(size_t)s * D_DIM + col] = (float)acc[mi][jt][r] * scv;
        }
      }
    }
  }
}

// ---------------------------------------------------------------------------
// Flash attention v5 = v4 body + XCD head clustering. Flat grid 1024; decode
// so blocks with B%8==x (-> XCD x under round-robin dispatch) cover heads
// 4x..4x+3 only: per-XCD K/V footprint 3 MB < 4 MB L2 (was 24 MB -> thrash).
// Block handles qt in {127-i, 64+i, 63-i, i} (uniform 66 key-tiles). Waves
// split key tiles; barrier-free K loop; f16 P; ones-MFMA denominator.
// ---------------------------------------------------------------------------
__global__ __launch_bounds__(256) void attn_mfma(
    const int8_t* __restrict__ q8, const int8_t* __restrict__ k8,
    const _Float16* __restrict__ vT, int8_t* __restrict__ o8) {
  const int B = blockIdx.x;
  const int xcd = B & 7, kdec = B >> 3;
  const int h = (xcd << 2) + (kdec & 3);  // heads clustered per XCD
  const int i = kdec >> 2;                // q-slice 0..31
  const int t = threadIdx.x;
  const int w = t >> 6, lane = t & 63, g = lane >> 4, l15 = lane & 15;

  // Pst[4][16][76] f32 (19456 B) aliased by merge Ol[64][68] f32 (17408 B)
  __shared__ __align__(16) float smem[4 * 16 * 76 + 128];
  float* Pw = smem + w * 16 * 76;
  float* Ml = smem + 4 * 16 * 76;
  float* Ll = Ml + 64;
  const float SSCALE = 8.838834764831845e-4f;  // 0.01 / sqrt(128)
  const v8h vones = {(_Float16)1, (_Float16)1, (_Float16)1, (_Float16)1,
                     (_Float16)1, (_Float16)1, (_Float16)1, (_Float16)1};

  const int qlist[4] = {127 - i, 64 + i, 63 - i, i};

  for (int it = 0; it < 4; ++it) {
    const int qt = qlist[it];
    const int q0 = qt * 16;
    const int T = (qt >> 2) + 1;  // number of 64-key tiles

    const v4i qa0 = *(const v4i*)(q8 + (size_t)(q0 + l15) * D_DIM + h * HDIM + g * 16);
    const v4i qa1 = *(const v4i*)(q8 + (size_t)(q0 + l15) * D_DIM + h * HDIM + 64 + g * 16);

    v4f o[8];
#pragma unroll
    for (int n = 0; n < 8; ++n) o[n] = (v4f){0.f, 0.f, 0.f, 0.f};
    v4f lacc = (v4f){0.f, 0.f, 0.f, 0.f};  // row-sums of f16 P via ones-MFMA
    float m_i[4] = {-INFINITY, -INFINITY, -INFINITY, -INFINITY};

    for (int kt = w; kt < T; kt += 4) {
      // ---- scores: int8 MFMA (exact int32) ----
      v4i s32[4];
#pragma unroll
      for (int nt = 0; nt < 4; ++nt) {
        const int key = kt * 64 + nt * 16 + l15;
        const v4i kb0 = *(const v4i*)(k8 + (size_t)key * D_DIM + h * HDIM + g * 16);
        const v4i kb1 = *(const v4i*)(k8 + (size_t)key * D_DIM + h * HDIM + 64 + g * 16);
        v4i c = (v4i){0, 0, 0, 0};
        c = __builtin_amdgcn_mfma_i32_16x16x64_i8(qa0, kb0, c, 0, 0, 0);
        c = __builtin_amdgcn_mfma_i32_16x16x64_i8(qa1, kb1, c, 0, 0, 0);
        s32[nt] = c;
      }
      float sc[4][4];
#pragma unroll
      for (int nt = 0; nt < 4; ++nt)
#pragma unroll
        for (int r = 0; r < 4; ++r) {
          float s = (float)s32[nt][r] * SSCALE;
          if (kt == T - 1) {  // only the last tile can cross the diagonal
            const int key = kt * 64 + nt * 16 + l15;
            const int q = q0 + g * 4 + r;
            if (key > q) s = -1.0e30f;
          }
          sc[nt][r] = s;
        }
      // ---- online softmax max + rescale ----
      float alpha[4];
#pragma unroll
      for (int r = 0; r < 4; ++r) {
        float mx = fmaxf(fmaxf(sc[0][r], sc[1][r]), fmaxf(sc[2][r], sc[3][r]));
#pragma unroll
        for (int off = 1; off < 16; off <<= 1) mx = fmaxf(mx, __shfl_xor(mx, off));
        const float mnew = fmaxf(m_i[r], mx);
        alpha[r] = __expf(m_i[r] - mnew);
        m_i[r] = mnew;
      }
#pragma unroll
      for (int nt = 0; nt < 4; ++nt)
#pragma unroll
        for (int r = 0; r < 4; ++r)
          Pw[(g * 4 + r) * 76 + nt * 16 + l15] = __expf(sc[nt][r] - m_i[r]);
#pragma unroll
      for (int nt = 0; nt < 8; ++nt)
#pragma unroll
        for (int r = 0; r < 4; ++r) o[nt][r] *= alpha[r];
#pragma unroll
      for (int r = 0; r < 4; ++r) lacc[r] *= alpha[r];

      // ---- P -> f16 A-frags (per-wave LDS round-trip, no barrier) ----
      v8h ph0, ph1;
      {
        const float* pr = &Pw[l15 * 76 + g * 8];
        const v4f pa = *(const v4f*)pr;
        const v4f pb = *(const v4f*)(pr + 4);
        const v4f pc = *(const v4f*)(pr + 32);
        const v4f pd = *(const v4f*)(pr + 36);
#pragma unroll
        for (int j = 0; j < 4; ++j) {
          ph0[j] = (_Float16)pa[j];
          ph0[4 + j] = (_Float16)pb[j];
          ph1[j] = (_Float16)pc[j];
          ph1[4 + j] = (_Float16)pd[j];
        }
      }
      // denominator rides on the MFMA pipe (B = ones)
      lacc = __builtin_amdgcn_mfma_f32_16x16x32_f16(ph0, vones, lacc, 0, 0, 0);
      lacc = __builtin_amdgcn_mfma_f32_16x16x32_f16(ph1, vones, lacc, 0, 0, 0);
      // ---- PV: f16 MFMA, V direct from global vT[d][s] f16 ----
#pragma unroll
      for (int nt = 0; nt < 8; ++nt) {
        const _Float16* vp =
            vT + (size_t)(h * HDIM + nt * 16 + l15) * S_LEN + kt * 64 + g * 8;
        const v8h v0 = *(const v8h*)vp;
        const v8h v1 = *(const v8h*)(vp + 32);
        o[nt] = __builtin_amdgcn_mfma_f32_16x16x32_f16(ph0, v0, o[nt], 0, 0, 0);
        o[nt] = __builtin_amdgcn_mfma_f32_16x16x32_f16(ph1, v1, o[nt], 0, 0, 0);
      }
    }

    // ---- merge the 4 waves' (m, l, O); two phases of 64 d ----
    if (l15 == 0) {
#pragma unroll
      for (int r = 0; r < 4; ++r) {
        Ml[w * 16 + g * 4 + r] = m_i[r];
        Ll[w * 16 + g * 4 + r] = lacc[r];
      }
    }
    __syncthreads();
    float scale[4];
#pragma unroll
    for (int r = 0; r < 4; ++r) {
      const int row = g * 4 + r;
      float M = fmaxf(fmaxf(Ml[row], Ml[16 + row]), fmaxf(Ml[32 + row], Ml[48 + row]));
      scale[r] = __expf(m_i[r] - M);  // 0 for idle waves (m=-inf)
    }
    float* Ol = smem;  // [4 waves][16 rows][68], aliases Pst (dead now)
    const int row = t >> 4, db4 = (t & 15) * 4;  // reduce mapping
#pragma unroll
    for (int ph = 0; ph < 2; ++ph) {
#pragma unroll
      for (int nt = 0; nt < 4; ++nt)
#pragma unroll
        for (int r = 0; r < 4; ++r)
          Ol[(w * 16 + g * 4 + r) * 68 + nt * 16 + l15] = o[ph * 4 + nt][r] * scale[r];
      __syncthreads();
      // reduce: thread -> (row, 4 d) of this 64-d phase
      float M = fmaxf(fmaxf(Ml[row], Ml[16 + row]), fmaxf(Ml[32 + row], Ml[48 + row]));
      float L = 0.f;
#pragma unroll
      for (int ww = 0; ww < 4; ++ww)
        L += __expf(Ml[ww * 16 + row] - M) * Ll[ww * 16 + row];
      unsigned pk = 0;
#pragma unroll
      for (int j = 0; j < 4; ++j) {
        float res = 0.f;
#pragma unroll
        for (int ww = 0; ww < 4; ++ww) res += Ol[(ww * 16 + row) * 68 + db4 + j];
        // out = res*0.1/L; out_q = rint(out/0.1) clamp +-127 (0.1 cancels)
        const int q = (int)fminf(fmaxf(rintf(res / L), -127.f), 127.f) & 0xff;
        pk |= (unsigned)q << (8 * j);
      }
      *(int*)(o8 + (size_t)(q0 + row) * D_DIM + h * HDIM + ph * 64 + db4) = (int)pk;
      __syncthreads();  // Ol reads done before next phase / next item
    }
  }
}

// ---------------------------------------------------------------------------
extern "C" void kernel_launch(void* const* d_in, const int* in_sizes, int n_in,
                              void* d_out, int out_size, void* d_ws, size_t ws_size,
                              hipStream_t stream) {
  (void)in_sizes; (void)n_in; (void)out_size; (void)ws_size;
  const float* hidden = (const float*)d_in[0];
  const float* wq = (const float*)d_in[1];
  const float* wk = (const float*)d_in[2];
  const float* wv = (const float*)d_in[3];
  const float* wo = (const float*)d_in[4];
  const float* sq = (const float*)d_in[5];
  const float* sk = (const float*)d_in[6];
  const float* sv = (const float*)d_in[7];
  const float* so = (const float*)d_in[8];
  // d_in[9] = attention_mask (pure causal; handled analytically)
  const int* pos = (const int*)d_in[10];
  float* out = (float*)d_out;

  char* ws = (char*)d_ws;
  int8_t* h8 = (int8_t*)ws;                                   // 8 MB (later o8)
  int8_t* q8 = (int8_t*)(ws + (8ull << 20));                  // 8 MB
  int8_t* k8 = (int8_t*)(ws + (16ull << 20));                 // 8 MB
  _Float16* vT = (_Float16*)(ws + (24ull << 20));             // 16 MB f16 [D][S]
  int8_t* w8a = (int8_t*)(ws + (40ull << 20));                // 16 MB (wq, later wo)
  int8_t* w8b = (int8_t*)(ws + (56ull << 20));                // 16 MB (wk)
  int8_t* w8c = (int8_t*)(ws + (72ull << 20));                // 16 MB (wv)
  float* ctab = (float*)(ws + (88ull << 20));                 // 512 KB
  float* stab = (float*)(ws + (88ull << 20) + (512ull << 10));
  int8_t* o8 = h8;  // h8 dead after v-GEMM; attn writes o8 there

  hipLaunchKernelGGL(rope_tab_k, dim3(512), dim3(256), 0, stream, pos, ctab, stab);
  hipLaunchKernelGGL(quant_hidden_k, dim3(8192), dim3(256), 0, stream, hidden, h8);
  hipLaunchKernelGGL(wconv3_k, dim3(49152), dim3(256), 0, stream, wq, wk, wv, w8a);

  const dim3 gg(512), gb(256);
  hipLaunchKernelGGL((gemm_i8<0>), gg, gb, 0, stream, h8, w8a, sq, ctab, stab, (void*)q8);
  hipLaunchKernelGGL((gemm_i8<1>), gg, gb, 0, stream, h8, w8b, sk, ctab, stab, (void*)k8);
  hipLaunchKernelGGL((gemm_i8<2>), gg, gb, 0, stream, h8, w8c, sv, ctab, stab, (void*)vT);
  hipLaunchKernelGGL(wconv_k, dim3(16384), dim3(256), 0, stream, wo, w8a);  // wq dead
  hipLaunchKernelGGL(attn_mfma, dim3(1024), dim3(256), 0, stream, q8, k8, vT, o8);
  hipLaunchKernelGGL((gemm_i8<3>), gg, gb, 0, stream, o8, w8a, so, ctab, stab, (void*)out);
}